// Round 1
// baseline (127.240 us; speedup 1.0000x reference)
//
#include <hip/hip_runtime.h>
#include <math.h>

#define NN 8192
#define DH 64
#define DOUT 10
#define NG 64      // number of graphs
#define NPG 128    // nodes per graph
#define NITER 5

// out[i,:] = relu( (sum_{j: adj[i,j]!=0} x[j,:] + x[i,:]) @ W + b )
// one wave per row, 4 waves / block of 256
__global__ __launch_bounds__(256) void spmm_lin_relu(
    const float* __restrict__ adj, const float* __restrict__ x,
    const float* __restrict__ W, const float* __restrict__ bias,
    float* __restrict__ out)
{
    __shared__ float sW[DH * DH];     // 16 KB
    __shared__ float sAcc[4][DH];

    for (int t = threadIdx.x; t < DH * DH; t += 256) sW[t] = W[t];

    const int wave = threadIdx.x >> 6;
    const int lane = threadIdx.x & 63;
    const int row  = (blockIdx.x << 2) + wave;

    // self-loop contribution
    float acc = x[row * DH + lane];

    const float* arow = adj + (size_t)row * NN;
    for (int j0 = 0; j0 < NN; j0 += 256) {
        float4 a4 = *reinterpret_cast<const float4*>(arow + j0 + lane * 4);
        unsigned long long m0 = __ballot(a4.x != 0.0f);
        unsigned long long m1 = __ballot(a4.y != 0.0f);
        unsigned long long m2 = __ballot(a4.z != 0.0f);
        unsigned long long m3 = __ballot(a4.w != 0.0f);
        while (m0) { int l = __ffsll((unsigned long long)m0) - 1; m0 &= m0 - 1; acc += x[(j0 + 4 * l + 0) * DH + lane]; }
        while (m1) { int l = __ffsll((unsigned long long)m1) - 1; m1 &= m1 - 1; acc += x[(j0 + 4 * l + 1) * DH + lane]; }
        while (m2) { int l = __ffsll((unsigned long long)m2) - 1; m2 &= m2 - 1; acc += x[(j0 + 4 * l + 2) * DH + lane]; }
        while (m3) { int l = __ffsll((unsigned long long)m3) - 1; m3 &= m3 - 1; acc += x[(j0 + 4 * l + 3) * DH + lane]; }
    }

    __syncthreads();            // sW ready + publish sAcc below
    sAcc[wave][lane] = acc;
    __syncthreads();

    float o = bias[lane];
    #pragma unroll
    for (int k = 0; k < DH; ++k) o += sAcc[wave][k] * sW[k * DH + lane];
    out[row * DH + lane] = fmaxf(o, 0.0f);
}

// One block (256 threads) per graph: power-iteration rs-pool + classifier + log_softmax
__global__ __launch_bounds__(256) void rspool_head(
    const float* __restrict__ h, const float* __restrict__ Wl,
    const float* __restrict__ bl, float* __restrict__ out)
{
    __shared__ float sX[NPG * 65];    // padded LD=65: conflict-free both axes
    __shared__ float sY[NPG];
    __shared__ float sVec[DH];
    __shared__ float sPart[4][DH];
    __shared__ float sPooled[DH];
    __shared__ float sO[DOUT];

    const int g = blockIdx.x;
    const int d = threadIdx.x & 63;
    const int q = threadIdx.x >> 6;

    // stage X_g = h[g*128 : (g+1)*128, :] into LDS (padded)
    const float* hg = h + (size_t)g * NPG * DH;
    for (int t = threadIdx.x; t < NPG * DH; t += 256)
        sX[(t >> 6) * 65 + (t & 63)] = hg[t];
    __syncthreads();

    // initial vec = column sums, normalized
    {
        float p = 0.0f;
        for (int i = q * 32; i < q * 32 + 32; ++i) p += sX[i * 65 + d];
        sPart[q][d] = p;
    }
    __syncthreads();
    if (threadIdx.x < 64) {
        float v = sPart[0][d] + sPart[1][d] + sPart[2][d] + sPart[3][d];
        float s = v * v;
        #pragma unroll
        for (int off = 32; off > 0; off >>= 1) s += __shfl_xor(s, off);
        sVec[d] = v / (sqrtf(s) + 1e-8f);
    }
    __syncthreads();

    for (int it = 0; it < NITER; ++it) {
        // y_i = X_i . vec
        if (threadIdx.x < NPG) {
            int i = threadIdx.x;
            float yy = 0.0f;
            #pragma unroll
            for (int dd = 0; dd < DH; ++dd) yy += sX[i * 65 + dd] * sVec[dd];
            sY[i] = yy;
        }
        __syncthreads();
        // vec = X^T y, normalized
        {
            float p = 0.0f;
            for (int i = q * 32; i < q * 32 + 32; ++i) p += sY[i] * sX[i * 65 + d];
            sPart[q][d] = p;
        }
        __syncthreads();
        if (threadIdx.x < 64) {
            float v = sPart[0][d] + sPart[1][d] + sPart[2][d] + sPart[3][d];
            float s = v * v;
            #pragma unroll
            for (int off = 32; off > 0; off >>= 1) s += __shfl_xor(s, off);
            sVec[d] = v / (sqrtf(s) + 1e-8f);
        }
        __syncthreads();
    }

    // final y with converged vec
    if (threadIdx.x < NPG) {
        int i = threadIdx.x;
        float yy = 0.0f;
        #pragma unroll
        for (int dd = 0; dd < DH; ++dd) yy += sX[i * 65 + dd] * sVec[dd];
        sY[i] = yy;
    }
    __syncthreads();
    if (threadIdx.x < 64) {
        float s = sY[d] * sY[d] + sY[64 + d] * sY[64 + d];
        #pragma unroll
        for (int off = 32; off > 0; off >>= 1) s += __shfl_xor(s, off);
        float sv = sqrtf(s);                 // ||X v|| ; VALUE_ALPHA = 1
        sPooled[d] = sVec[d] * sv;
    }
    __syncthreads();

    if (threadIdx.x < DOUT) {
        int c = threadIdx.x;
        float o = bl[c];
        #pragma unroll
        for (int dd = 0; dd < DH; ++dd) o += sPooled[dd] * Wl[dd * DOUT + c];
        sO[c] = o;
    }
    __syncthreads();
    if (threadIdx.x < DOUT) {
        int c = threadIdx.x;
        float mx = -INFINITY;
        #pragma unroll
        for (int j = 0; j < DOUT; ++j) mx = fmaxf(mx, sO[j]);
        float se = 0.0f;
        #pragma unroll
        for (int j = 0; j < DOUT; ++j) se += expf(sO[j] - mx);
        out[g * DOUT + c] = sO[c] - mx - logf(se);
    }
}

extern "C" void kernel_launch(void* const* d_in, const int* in_sizes, int n_in,
                              void* d_out, int out_size, void* d_ws, size_t ws_size,
                              hipStream_t stream) {
    const float* x_in = (const float*)d_in[0];
    const float* adj  = (const float*)d_in[1];
    // d_in[2] = idx (graphs are contiguous 128-node blocks by construction)
    const float* W1 = (const float*)d_in[3];
    const float* b1 = (const float*)d_in[4];
    const float* W2 = (const float*)d_in[5];
    const float* b2 = (const float*)d_in[6];
    const float* Wl = (const float*)d_in[7];
    const float* bl = (const float*)d_in[8];
    float* out = (float*)d_out;

    float* h1 = (float*)d_ws;            // [8192,64]
    float* h2 = h1 + NN * DH;            // [8192,64]

    spmm_lin_relu<<<NN / 4, 256, 0, stream>>>(adj, x_in, W1, b1, h1);
    spmm_lin_relu<<<NN / 4, 256, 0, stream>>>(adj, h1,  W2, b2, h2);
    rspool_head<<<NG, 256, 0, stream>>>(h2, Wl, bl, out);
}

// Round 2
// 117.301 us; speedup vs baseline: 1.0847x; 1.0847x over previous
//
#include <hip/hip_runtime.h>
#include <math.h>

#define NN 8192
#define DH 64
#define DOUT 10
#define NG 64      // number of graphs
#define NPG 128    // nodes per graph
#define NITER 5
#define CAP 192    // max stored neighbors per row
#define CAPW 96    // max per quarter-row (per wave in pass 1)

// Pass 1: one block per row. 4 waves each scan 2048 columns of adj (float4 +
// ballot), accumulate gathered x rows, emit neighbor indices (ushort) to LDS,
// then merge: edge list -> global, reduced acc -> 64x64 linear + ReLU -> h1.
__global__ __launch_bounds__(256) void gin1_scan(
    const float* __restrict__ adj, const float* __restrict__ x,
    const float* __restrict__ W, const float* __restrict__ bias,
    float* __restrict__ h, unsigned short* __restrict__ eidx,
    int* __restrict__ counts)
{
    __shared__ float sW[DH * DH];            // 16 KB
    __shared__ float sAccP[4][DH];
    __shared__ float sAccR[DH];
    __shared__ unsigned short sIdx[4][CAPW];
    __shared__ int sCnt[4];

    for (int t = threadIdx.x; t < DH * DH; t += 256) sW[t] = W[t];

    const int wave = threadIdx.x >> 6;
    const int lane = threadIdx.x & 63;
    const int row  = blockIdx.x;

    float acc = (wave == 0) ? x[row * DH + lane] : 0.0f;   // self-loop (+I)

    const float* arow = adj + (size_t)row * NN + wave * 2048;
    int ec = 0;
    for (int j0 = 0; j0 < 2048; j0 += 256) {
        float4 a4 = *reinterpret_cast<const float4*>(arow + j0 + lane * 4);
        unsigned long long m0 = __ballot(a4.x != 0.0f);
        unsigned long long m1 = __ballot(a4.y != 0.0f);
        unsigned long long m2 = __ballot(a4.z != 0.0f);
        unsigned long long m3 = __ballot(a4.w != 0.0f);
        int base = wave * 2048 + j0;
        while (m0) { int l = __ffsll(m0) - 1; m0 &= m0 - 1; int j = base + 4 * l + 0;
                     acc += x[j * DH + lane]; if (lane == 0) sIdx[wave][ec] = (unsigned short)j; ++ec; }
        while (m1) { int l = __ffsll(m1) - 1; m1 &= m1 - 1; int j = base + 4 * l + 1;
                     acc += x[j * DH + lane]; if (lane == 0) sIdx[wave][ec] = (unsigned short)j; ++ec; }
        while (m2) { int l = __ffsll(m2) - 1; m2 &= m2 - 1; int j = base + 4 * l + 2;
                     acc += x[j * DH + lane]; if (lane == 0) sIdx[wave][ec] = (unsigned short)j; ++ec; }
        while (m3) { int l = __ffsll(m3) - 1; m3 &= m3 - 1; int j = base + 4 * l + 3;
                     acc += x[j * DH + lane]; if (lane == 0) sIdx[wave][ec] = (unsigned short)j; ++ec; }
    }

    sAccP[wave][lane] = acc;
    if (lane == 0) sCnt[wave] = ec;
    __syncthreads();

    // concatenate the 4 per-wave edge segments in wave order (deterministic)
    int c0 = sCnt[0], c1 = sCnt[1], c2 = sCnt[2], c3 = sCnt[3];
    int off = (wave > 0 ? c0 : 0) + (wave > 1 ? c1 : 0) + (wave > 2 ? c2 : 0);
    for (int e = lane; e < sCnt[wave]; e += 64)
        eidx[(size_t)row * CAP + off + e] = sIdx[wave][e];
    if (threadIdx.x == 0) counts[row] = c0 + c1 + c2 + c3;

    if (wave == 0) {
        float a = sAccP[0][lane] + sAccP[1][lane] + sAccP[2][lane] + sAccP[3][lane];
        sAccR[lane] = a;
        float o = bias[lane];
        #pragma unroll
        for (int k = 0; k < DH; ++k) o += sAccR[k] * sW[k * DH + lane];
        h[row * DH + lane] = fmaxf(o, 0.0f);
    }
}

// Pass 2: edge-list GIN layer. One wave per row, 4 rows per block.
__global__ __launch_bounds__(256) void gin2_edges(
    const float* __restrict__ x, const unsigned short* __restrict__ eidx,
    const int* __restrict__ counts, const float* __restrict__ W,
    const float* __restrict__ bias, float* __restrict__ out)
{
    __shared__ float sW[DH * DH];
    __shared__ float sAcc[4][DH];
    __shared__ unsigned short sIdx[4][CAP];

    for (int t = threadIdx.x; t < DH * DH; t += 256) sW[t] = W[t];

    const int wave = threadIdx.x >> 6;
    const int lane = threadIdx.x & 63;
    const int row  = (blockIdx.x << 2) + wave;

    const int ec = counts[row];
    for (int e = lane; e < ec; e += 64) sIdx[wave][e] = eidx[(size_t)row * CAP + e];
    __syncthreads();

    float acc = x[row * DH + lane];            // self-loop
    for (int e = 0; e < ec; ++e) {
        int j = sIdx[wave][e];                  // LDS broadcast (uniform)
        acc += x[j * DH + lane];
    }

    sAcc[wave][lane] = acc;
    __syncthreads();

    float o = bias[lane];
    #pragma unroll
    for (int k = 0; k < DH; ++k) o += sAcc[wave][k] * sW[k * DH + lane];
    out[row * DH + lane] = fmaxf(o, 0.0f);
}

// One block (256 threads) per graph: power-iteration rs-pool + classifier + log_softmax
__global__ __launch_bounds__(256) void rspool_head(
    const float* __restrict__ h, const float* __restrict__ Wl,
    const float* __restrict__ bl, float* __restrict__ out)
{
    __shared__ float sX[NPG * 65];    // padded LD=65: conflict-free both axes
    __shared__ float sY[NPG];
    __shared__ float sVec[DH];
    __shared__ float sPart[4][DH];
    __shared__ float sPooled[DH];
    __shared__ float sO[DOUT];

    const int g = blockIdx.x;
    const int d = threadIdx.x & 63;
    const int q = threadIdx.x >> 6;

    const float* hg = h + (size_t)g * NPG * DH;
    for (int t = threadIdx.x; t < NPG * DH; t += 256)
        sX[(t >> 6) * 65 + (t & 63)] = hg[t];
    __syncthreads();

    {
        float p = 0.0f;
        for (int i = q * 32; i < q * 32 + 32; ++i) p += sX[i * 65 + d];
        sPart[q][d] = p;
    }
    __syncthreads();
    if (threadIdx.x < 64) {
        float v = sPart[0][d] + sPart[1][d] + sPart[2][d] + sPart[3][d];
        float s = v * v;
        #pragma unroll
        for (int off = 32; off > 0; off >>= 1) s += __shfl_xor(s, off);
        sVec[d] = v / (sqrtf(s) + 1e-8f);
    }
    __syncthreads();

    for (int it = 0; it < NITER; ++it) {
        if (threadIdx.x < NPG) {
            int i = threadIdx.x;
            float yy = 0.0f;
            #pragma unroll
            for (int dd = 0; dd < DH; ++dd) yy += sX[i * 65 + dd] * sVec[dd];
            sY[i] = yy;
        }
        __syncthreads();
        {
            float p = 0.0f;
            for (int i = q * 32; i < q * 32 + 32; ++i) p += sY[i] * sX[i * 65 + d];
            sPart[q][d] = p;
        }
        __syncthreads();
        if (threadIdx.x < 64) {
            float v = sPart[0][d] + sPart[1][d] + sPart[2][d] + sPart[3][d];
            float s = v * v;
            #pragma unroll
            for (int off = 32; off > 0; off >>= 1) s += __shfl_xor(s, off);
            sVec[d] = v / (sqrtf(s) + 1e-8f);
        }
        __syncthreads();
    }

    if (threadIdx.x < NPG) {
        int i = threadIdx.x;
        float yy = 0.0f;
        #pragma unroll
        for (int dd = 0; dd < DH; ++dd) yy += sX[i * 65 + dd] * sVec[dd];
        sY[i] = yy;
    }
    __syncthreads();
    if (threadIdx.x < 64) {
        float s = sY[d] * sY[d] + sY[64 + d] * sY[64 + d];
        #pragma unroll
        for (int off = 32; off > 0; off >>= 1) s += __shfl_xor(s, off);
        float sv = sqrtf(s);
        sPooled[d] = sVec[d] * sv;
    }
    __syncthreads();

    if (threadIdx.x < DOUT) {
        int c = threadIdx.x;
        float o = bl[c];
        #pragma unroll
        for (int dd = 0; dd < DH; ++dd) o += sPooled[dd] * Wl[dd * DOUT + c];
        sO[c] = o;
    }
    __syncthreads();
    if (threadIdx.x < DOUT) {
        int c = threadIdx.x;
        float mx = -INFINITY;
        #pragma unroll
        for (int j = 0; j < DOUT; ++j) mx = fmaxf(mx, sO[j]);
        float se = 0.0f;
        #pragma unroll
        for (int j = 0; j < DOUT; ++j) se += expf(sO[j] - mx);
        out[g * DOUT + c] = sO[c] - mx - logf(se);
    }
}

extern "C" void kernel_launch(void* const* d_in, const int* in_sizes, int n_in,
                              void* d_out, int out_size, void* d_ws, size_t ws_size,
                              hipStream_t stream) {
    const float* x_in = (const float*)d_in[0];
    const float* adj  = (const float*)d_in[1];
    // d_in[2] = idx (graphs are contiguous 128-node blocks by construction)
    const float* W1 = (const float*)d_in[3];
    const float* b1 = (const float*)d_in[4];
    const float* W2 = (const float*)d_in[5];
    const float* b2 = (const float*)d_in[6];
    const float* Wl = (const float*)d_in[7];
    const float* bl = (const float*)d_in[8];
    float* out = (float*)d_out;

    char* ws = (char*)d_ws;
    float* h1 = (float*)ws;                                   // 2 MB
    float* h2 = h1 + NN * DH;                                 // 2 MB
    int*   counts = (int*)(ws + 4 * 1024 * 1024);             // 32 KB
    unsigned short* eidx = (unsigned short*)(ws + 5 * 1024 * 1024);  // 3.1 MB

    gin1_scan<<<NN, 256, 0, stream>>>(adj, x_in, W1, b1, h1, eidx, counts);
    gin2_edges<<<NN / 4, 256, 0, stream>>>(h1, eidx, counts, W2, b2, h2);
    rspool_head<<<NG, 256, 0, stream>>>(h2, Wl, bl, out);
}

// Round 3
// 98.563 us; speedup vs baseline: 1.2909x; 1.1901x over previous
//
#include <hip/hip_runtime.h>
#include <math.h>

#define NN 8192
#define DH 64
#define DOUT 10
#define NG 64      // number of graphs
#define NPG 128    // nodes per graph
#define NITER 5
#define CAP 192    // max stored neighbors per row
#define CAPW 96    // max per quarter-row (per wave in pass 1)

// Fused pass 1: one block per row.
// Phase A (streaming): 4 waves scan 2048 adj columns each, fully unrolled
//   float4 loads + ballot + PARALLEL prefix-popcount index extraction to LDS.
// Phase B (gather): each wave accumulates x rows for its own edge segment
//   (independent loads, compiler-pipelined), then reduce + 64x64 linear+ReLU.
__global__ __launch_bounds__(256) void gin1_fused(
    const float* __restrict__ adj, const float* __restrict__ x,
    const float* __restrict__ W, const float* __restrict__ bias,
    float* __restrict__ h, unsigned short* __restrict__ eidx,
    int* __restrict__ counts)
{
    __shared__ float sW[DH * DH];            // 16 KB
    __shared__ float sAccP[4][DH];
    __shared__ float sAccR[DH];
    __shared__ unsigned short sIdx[4][CAPW];
    __shared__ int sCnt[4];

    for (int t = threadIdx.x; t < DH * DH; t += 256) sW[t] = W[t];

    const int wave = threadIdx.x >> 6;
    const int lane = threadIdx.x & 63;
    const int row  = blockIdx.x;

    const float* arow = adj + (size_t)row * NN + wave * 2048;
    const unsigned long long lt = (lane == 63) ? 0x7FFFFFFFFFFFFFFFull
                                               : ((1ull << lane) - 1ull);
    int ec = 0;
    #pragma unroll
    for (int j0 = 0; j0 < 2048; j0 += 256) {
        float4 a4 = *reinterpret_cast<const float4*>(arow + j0 + lane * 4);
        unsigned long long m0 = __ballot(a4.x != 0.0f);
        unsigned long long m1 = __ballot(a4.y != 0.0f);
        unsigned long long m2 = __ballot(a4.z != 0.0f);
        unsigned long long m3 = __ballot(a4.w != 0.0f);
        int pre = __popcll(m0 & lt) + __popcll(m1 & lt) +
                  __popcll(m2 & lt) + __popcll(m3 & lt);
        int pos = ec + pre;
        int jb = wave * 2048 + j0 + 4 * lane;
        if ((m0 >> lane) & 1) sIdx[wave][pos++] = (unsigned short)(jb + 0);
        if ((m1 >> lane) & 1) sIdx[wave][pos++] = (unsigned short)(jb + 1);
        if ((m2 >> lane) & 1) sIdx[wave][pos++] = (unsigned short)(jb + 2);
        if ((m3 >> lane) & 1) sIdx[wave][pos++] = (unsigned short)(jb + 3);
        ec += __popcll(m0) + __popcll(m1) + __popcll(m2) + __popcll(m3);
    }
    if (lane == 0) sCnt[wave] = ec;
    __syncthreads();

    // write edge list to global, concatenated in wave order (deterministic)
    int c0 = sCnt[0], c1 = sCnt[1], c2 = sCnt[2], c3 = sCnt[3];
    int off = (wave > 0 ? c0 : 0) + (wave > 1 ? c1 : 0) + (wave > 2 ? c2 : 0);
    for (int e = lane; e < ec; e += 64)
        eidx[(size_t)row * CAP + off + e] = sIdx[wave][e];
    if (threadIdx.x == 0) counts[row] = c0 + c1 + c2 + c3;

    // Phase B: gather. Independent loads, pipelined by the compiler.
    float acc = (wave == 0) ? x[row * DH + lane] : 0.0f;   // self-loop
    #pragma unroll 4
    for (int e = 0; e < ec; ++e) {
        int j = sIdx[wave][e];               // wave-uniform LDS broadcast
        acc += x[j * DH + lane];
    }
    sAccP[wave][lane] = acc;
    __syncthreads();

    if (wave == 0) {
        float a = sAccP[0][lane] + sAccP[1][lane] + sAccP[2][lane] + sAccP[3][lane];
        sAccR[lane] = a;
        float o = bias[lane];
        #pragma unroll
        for (int k = 0; k < DH; ++k) o += sAccR[k] * sW[k * DH + lane];
        h[row * DH + lane] = fmaxf(o, 0.0f);
    }
}

// Pass 2: edge-list GIN layer. One wave per row, 4 rows per block.
__global__ __launch_bounds__(256) void gin2_edges(
    const float* __restrict__ x, const unsigned short* __restrict__ eidx,
    const int* __restrict__ counts, const float* __restrict__ W,
    const float* __restrict__ bias, float* __restrict__ out)
{
    __shared__ float sW[DH * DH];
    __shared__ float sAcc[4][DH];
    __shared__ unsigned short sIdx[4][CAP];

    for (int t = threadIdx.x; t < DH * DH; t += 256) sW[t] = W[t];

    const int wave = threadIdx.x >> 6;
    const int lane = threadIdx.x & 63;
    const int row  = (blockIdx.x << 2) + wave;

    const int ec = counts[row];
    for (int e = lane; e < ec; e += 64) sIdx[wave][e] = eidx[(size_t)row * CAP + e];
    __syncthreads();

    float acc = x[row * DH + lane];            // self-loop
    #pragma unroll 4
    for (int e = 0; e < ec; ++e) {
        int j = sIdx[wave][e];                  // LDS broadcast (uniform)
        acc += x[j * DH + lane];
    }

    sAcc[wave][lane] = acc;
    __syncthreads();

    float o = bias[lane];
    #pragma unroll
    for (int k = 0; k < DH; ++k) o += sAcc[wave][k] * sW[k * DH + lane];
    out[row * DH + lane] = fmaxf(o, 0.0f);
}

// One block (256 threads) per graph: power-iteration rs-pool + classifier + log_softmax
__global__ __launch_bounds__(256) void rspool_head(
    const float* __restrict__ h, const float* __restrict__ Wl,
    const float* __restrict__ bl, float* __restrict__ out)
{
    __shared__ float sX[NPG * 65];    // padded LD=65: conflict-free both axes
    __shared__ float sY[NPG];
    __shared__ float sVec[DH];
    __shared__ float sPart[4][DH];
    __shared__ float sPooled[DH];
    __shared__ float sO[DOUT];

    const int g = blockIdx.x;
    const int d = threadIdx.x & 63;
    const int q = threadIdx.x >> 6;

    const float* hg = h + (size_t)g * NPG * DH;
    for (int t = threadIdx.x; t < NPG * DH; t += 256)
        sX[(t >> 6) * 65 + (t & 63)] = hg[t];
    __syncthreads();

    {
        float p = 0.0f;
        for (int i = q * 32; i < q * 32 + 32; ++i) p += sX[i * 65 + d];
        sPart[q][d] = p;
    }
    __syncthreads();
    if (threadIdx.x < 64) {
        float v = sPart[0][d] + sPart[1][d] + sPart[2][d] + sPart[3][d];
        float s = v * v;
        #pragma unroll
        for (int off = 32; off > 0; off >>= 1) s += __shfl_xor(s, off);
        sVec[d] = v / (sqrtf(s) + 1e-8f);
    }
    __syncthreads();

    for (int it = 0; it < NITER; ++it) {
        if (threadIdx.x < NPG) {
            int i = threadIdx.x;
            float yy = 0.0f;
            #pragma unroll
            for (int dd = 0; dd < DH; ++dd) yy += sX[i * 65 + dd] * sVec[dd];
            sY[i] = yy;
        }
        __syncthreads();
        {
            float p = 0.0f;
            for (int i = q * 32; i < q * 32 + 32; ++i) p += sY[i] * sX[i * 65 + d];
            sPart[q][d] = p;
        }
        __syncthreads();
        if (threadIdx.x < 64) {
            float v = sPart[0][d] + sPart[1][d] + sPart[2][d] + sPart[3][d];
            float s = v * v;
            #pragma unroll
            for (int off = 32; off > 0; off >>= 1) s += __shfl_xor(s, off);
            sVec[d] = v / (sqrtf(s) + 1e-8f);
        }
        __syncthreads();
    }

    if (threadIdx.x < NPG) {
        int i = threadIdx.x;
        float yy = 0.0f;
        #pragma unroll
        for (int dd = 0; dd < DH; ++dd) yy += sX[i * 65 + dd] * sVec[dd];
        sY[i] = yy;
    }
    __syncthreads();
    if (threadIdx.x < 64) {
        float s = sY[d] * sY[d] + sY[64 + d] * sY[64 + d];
        #pragma unroll
        for (int off = 32; off > 0; off >>= 1) s += __shfl_xor(s, off);
        float sv = sqrtf(s);
        sPooled[d] = sVec[d] * sv;
    }
    __syncthreads();

    if (threadIdx.x < DOUT) {
        int c = threadIdx.x;
        float o = bl[c];
        #pragma unroll
        for (int dd = 0; dd < DH; ++dd) o += sPooled[dd] * Wl[dd * DOUT + c];
        sO[c] = o;
    }
    __syncthreads();
    if (threadIdx.x < DOUT) {
        int c = threadIdx.x;
        float mx = -INFINITY;
        #pragma unroll
        for (int j = 0; j < DOUT; ++j) mx = fmaxf(mx, sO[j]);
        float se = 0.0f;
        #pragma unroll
        for (int j = 0; j < DOUT; ++j) se += expf(sO[j] - mx);
        out[g * DOUT + c] = sO[c] - mx - logf(se);
    }
}

extern "C" void kernel_launch(void* const* d_in, const int* in_sizes, int n_in,
                              void* d_out, int out_size, void* d_ws, size_t ws_size,
                              hipStream_t stream) {
    const float* x_in = (const float*)d_in[0];
    const float* adj  = (const float*)d_in[1];
    // d_in[2] = idx (graphs are contiguous 128-node blocks by construction)
    const float* W1 = (const float*)d_in[3];
    const float* b1 = (const float*)d_in[4];
    const float* W2 = (const float*)d_in[5];
    const float* b2 = (const float*)d_in[6];
    const float* Wl = (const float*)d_in[7];
    const float* bl = (const float*)d_in[8];
    float* out = (float*)d_out;

    char* ws = (char*)d_ws;
    float* h1 = (float*)ws;                                   // 2 MB
    float* h2 = h1 + NN * DH;                                 // 2 MB
    int*   counts = (int*)(ws + 4 * 1024 * 1024);             // 32 KB
    unsigned short* eidx = (unsigned short*)(ws + 5 * 1024 * 1024);  // 3.1 MB

    gin1_fused<<<NN, 256, 0, stream>>>(adj, x_in, W1, b1, h1, eidx, counts);
    gin2_edges<<<NN / 4, 256, 0, stream>>>(h1, eidx, counts, W2, b2, h2);
    rspool_head<<<NG, 256, 0, stream>>>(h2, Wl, bl, out);
}